// Round 9
// baseline (3521.955 us; speedup 1.0000x reference)
//
#include <hip/hip_runtime.h>

#define DEVINL __device__ __forceinline__

constexpr int J_ = 3000;   // frames
constexpr int I_ = 2049;   // freq bins
constexpr int K_ = 8;      // NMF bases
constexpr int NITER = 30;
constexpr float EPS = 1e-20f;  // NMF_EPS == IP_EPS
constexpr int JH = 1500;       // real j-pairs per row
constexpr int JHP = 1536;      // padded j-pairs (6*256)
constexpr int JP = 2 * JHP;    // padded j count = 3072
constexpr int NL = JHP / 256;  // 6 uniform loop iterations
constexpr int TJB = 256;
constexpr int NJTP = JHP / TJB;  // 6

typedef float f32x2 __attribute__((ext_vector_type(2)));

DEVINL float waveRed(float v) {
#pragma unroll
  for (int off = 32; off > 0; off >>= 1) v += __shfl_xor(v, off, 64);
  return v;
}

DEVINL float frcp(float x) { return __builtin_amdgcn_rcpf(x); }  // ~1 ulp
DEVINL f32x2 sp(float s) { return (f32x2){s, s}; }
DEVINL f32x2 xy(float4 v) { return (f32x2){v.x, v.y}; }
DEVINL f32x2 zw(float4 v) { return (f32x2){v.z, v.w}; }

// ---------------- init: T -> (n,i,k); V copy (padded, zero-fill); W = identity ----------------
__global__ void k_init(const float* __restrict__ Tin, const float* __restrict__ Vin,
                       float* __restrict__ T, float2* __restrict__ V2, float2* __restrict__ W2) {
  int idx = blockIdx.x * 256 + threadIdx.x;
  if (idx < I_ * K_ * 2) {
    int n = idx & 1, rem = idx >> 1;  // idx = (i*K + k)*2 + n
    int k = rem & 7, i = rem >> 3;
    T[n * I_ * K_ + i * K_ + k] = Tin[idx];
  }
  if (idx < K_ * JP) {
    int k = idx / JP, j = idx - k * JP;
    float2 v = (j < J_) ? ((const float2*)Vin)[k * J_ + j] : make_float2(0.f, 0.f);
    V2[k * JP + j] = v;
  }
  if (idx < I_) {
    W2[idx * 4 + 0] = make_float2(1.f, 0.f);
    W2[idx * 4 + 1] = make_float2(0.f, 0.f);
    W2[idx * 4 + 2] = make_float2(0.f, 0.f);
    W2[idx * 4 + 3] = make_float2(1.f, 0.f);
  }
}

// ------- transpose X (M,J,I) cplx -> Xt (M,I,JP) cplx, zero-padding j in [J_,JP) -------
__global__ __launch_bounds__(256) void k_transpose(const float2* __restrict__ X, float2* __restrict__ Xt) {
  __shared__ float2 tile[32][33];
  int m = blockIdx.z;
  int i0 = blockIdx.x * 32, j0 = blockIdx.y * 32;
  int tx = threadIdx.x & 31, ty = threadIdx.x >> 5;
  for (int r = ty; r < 32; r += 8) {
    int j = j0 + r, i = i0 + tx;
    tile[r][tx] = (i < I_ && j < J_) ? X[((size_t)m * J_ + j) * I_ + i] : make_float2(0.f, 0.f);
  }
  __syncthreads();
  for (int r = ty; r < 32; r += 8) {
    int i = i0 + r, j = j0 + tx;
    if (i < I_) Xt[((size_t)m * I_ + i) * JP + j] = tile[tx][r];
  }
}

// ============ fused kernel: [C(t): D + IP -> W_new] + [A(t+1): YdR + T update] ============
// Phase C computes R = T.V once; carries it to phase A through LDS (same-thread, no barrier).
// unroll 3 on both j-loops: raises outstanding-load count (MLP) ~1.5-3x — the r8 PMC
// analysis showed supply ~8 B/cy/CU vs ~24 B/cy demand (latency-parallelism bound).
template <bool DO_C, bool DO_A>
__global__ __launch_bounds__(256, 4) void k_CA(const float4* __restrict__ Xt4,  // (2,I,JHP)
                                               float2* __restrict__ W2,
                                               float* __restrict__ T,           // (2,I,K)
                                               const float4* __restrict__ V4,   // (K,JHP) {v0a,v1a,v0b,v1b}
                                               float2* __restrict__ YdR2) {     // (2,I,JHP)
  const int i = blockIdx.x, t = threadIdx.x;
  const int wave = t >> 6, lane = t & 63;
  f32x2 Tp[K_];  // {T0[k], T1[k]}
#pragma unroll
  for (int k = 0; k < K_; k++) {
    Tp[k] = (f32x2){T[i * K_ + k], T[I_ * K_ + i * K_ + k]};
  }
  const float4* x0r = Xt4 + (size_t)i * JHP;
  const float4* x1r = Xt4 + (size_t)(I_ + i) * JHP;

  __shared__ f32x2 sR[2][NL][256];  // R carried C->A per (a/b, window, thread); 24 KB
  __shared__ float sred[4][32];
  __shared__ float sout[32];
  __shared__ float sbc[8];  // alpha,beta,gamma,delta per source

  if constexpr (DO_C) {
    f32x2 an00 = sp(0.f), an11 = sp(0.f), acre = sp(0.f), acim = sp(0.f);  // {src0,src1}
#pragma unroll 3
    for (int l = 0; l < NL; l++) {
      int j2 = t + l * 256;
      float4 x0 = x0r[j2], x1 = x1r[j2];
      f32x2 rA = sp(0.f), rB = sp(0.f);
#pragma unroll
      for (int k = 0; k < K_; k++) {
        float4 vp = V4[(size_t)k * JHP + j2];
        rA += Tp[k] * xy(vp);
        rB += Tp[k] * zw(vp);
      }
      if constexpr (DO_A) {
        sR[0][l][t] = rA;
        sR[1][l][t] = rB;
      }
      f32x2 iA = (f32x2){frcp(rA.x + EPS), frcp(rA.y + EPS)};
      f32x2 iB = (f32x2){frcp(rB.x + EPS), frcp(rB.y + EPS)};
      float n00a = x0.x * x0.x + x0.y * x0.y, n00b = x0.z * x0.z + x0.w * x0.w;
      float n11a = x1.x * x1.x + x1.y * x1.y, n11b = x1.z * x1.z + x1.w * x1.w;
      float crea = x0.x * x1.x + x0.y * x1.y, creb = x0.z * x1.z + x0.w * x1.w;
      float cima = x0.y * x1.x - x0.x * x1.y, cimb = x0.w * x1.z - x0.z * x1.w;
      an00 += sp(n00a) * iA + sp(n00b) * iB;
      an11 += sp(n11a) * iA + sp(n11b) * iB;
      acre += sp(crea) * iA + sp(creb) * iB;
      acim += sp(cima) * iA + sp(cimb) * iB;
    }
    float vals[8] = {an00.x, an11.x, acre.x, acim.x, an00.y, an11.y, acre.y, acim.y};
#pragma unroll
    for (int q = 0; q < 8; q++) {
      float v = waveRed(vals[q]);
      if (lane == 0) sred[wave][q] = v;
    }
    __syncthreads();
    if (t < 8) sout[t] = sred[0][t] + sred[1][t] + sred[2][t] + sred[3][t];
    __syncthreads();
    if (t == 0) {
      const double Jinv = 1.0 / (double)J_;
      double D[2][4];
#pragma unroll
      for (int s2 = 0; s2 < 2; s2++) {
        D[s2][0] = (double)sout[s2 * 4 + 0] * Jinv + (double)EPS;
        D[s2][1] = (double)sout[s2 * 4 + 1] * Jinv + (double)EPS;
        D[s2][2] = (double)sout[s2 * 4 + 2] * Jinv;
        D[s2][3] = (double)sout[s2 * 4 + 3] * Jinv;
      }
      double Wd[2][2][2];
#pragma unroll
      for (int r = 0; r < 2; r++)
#pragma unroll
        for (int c = 0; c < 2; c++) {
          float2 w = W2[i * 4 + r * 2 + c];
          Wd[r][c][0] = w.x;
          Wd[r][c][1] = w.y;
        }
      for (int n2 = 0; n2 < 2; n2++) {
        double d00 = D[n2][0], d11 = D[n2][1], dre = D[n2][2], dim = D[n2][3];
        double A[2][2][2];
#pragma unroll
        for (int r = 0; r < 2; r++) {
          A[r][0][0] = Wd[r][0][0] * d00 + (Wd[r][1][0] * dre + Wd[r][1][1] * dim);
          A[r][0][1] = Wd[r][0][1] * d00 + (Wd[r][1][1] * dre - Wd[r][1][0] * dim);
          A[r][1][0] = Wd[r][1][0] * d11 + (Wd[r][0][0] * dre - Wd[r][0][1] * dim);
          A[r][1][1] = Wd[r][1][1] * d11 + (Wd[r][0][1] * dre + Wd[r][0][0] * dim);
        }
        double detre = A[0][0][0] * A[1][1][0] - A[0][0][1] * A[1][1][1]
                     - (A[0][1][0] * A[1][0][0] - A[0][1][1] * A[1][0][1]);
        double detim = A[0][0][0] * A[1][1][1] + A[0][0][1] * A[1][1][0]
                     - (A[0][1][0] * A[1][0][1] + A[0][1][1] * A[1][0][0]);
        double b0re, b0im, b1re, b1im;
        if (n2 == 0) { b0re = A[1][1][0]; b0im = A[1][1][1]; b1re = -A[1][0][0]; b1im = -A[1][0][1]; }
        else         { b0re = -A[0][1][0]; b0im = -A[0][1][1]; b1re = A[0][0][0]; b1im = A[0][0][1]; }
        double dmag = detre * detre + detim * detim;
        double t0re = (b0re * detre + b0im * detim) / dmag, t0im = (b0im * detre - b0re * detim) / dmag;
        double t1re = (b1re * detre + b1im * detim) / dmag, t1im = (b1im * detre - b1re * detim) / dmag;
        double pre = t0re * t1re + t0im * t1im, pim = t0re * t1im - t0im * t1re;
        double quad = d00 * (t0re * t0re + t0im * t0im) + d11 * (t1re * t1re + t1im * t1im)
                    + 2.0 * (dre * pre - dim * pim);
        double denom = sqrt(quad + (double)EPS);
        double w0re = t0re / denom, w0im = -t0im / denom;
        double w1re = t1re / denom, w1im = -t1im / denom;
        Wd[n2][0][0] = w0re; Wd[n2][0][1] = w0im;
        Wd[n2][1][0] = w1re; Wd[n2][1][1] = w1im;
        W2[i * 4 + n2 * 2 + 0] = make_float2((float)w0re, (float)w0im);
        W2[i * 4 + n2 * 2 + 1] = make_float2((float)w1re, (float)w1im);
      }
      if (DO_A) {
        sbc[0] = (float)(Wd[0][0][0] * Wd[0][0][0] + Wd[0][0][1] * Wd[0][0][1]);
        sbc[1] = (float)(Wd[0][1][0] * Wd[0][1][0] + Wd[0][1][1] * Wd[0][1][1]);
        sbc[2] = (float)(2.0 * (Wd[0][0][0] * Wd[0][1][0] + Wd[0][0][1] * Wd[0][1][1]));
        sbc[3] = (float)(-2.0 * (Wd[0][0][1] * Wd[0][1][0] - Wd[0][0][0] * Wd[0][1][1]));
        sbc[4] = (float)(Wd[1][0][0] * Wd[1][0][0] + Wd[1][0][1] * Wd[1][0][1]);
        sbc[5] = (float)(Wd[1][1][0] * Wd[1][1][0] + Wd[1][1][1] * Wd[1][1][1]);
        sbc[6] = (float)(2.0 * (Wd[1][0][0] * Wd[1][1][0] + Wd[1][0][1] * Wd[1][1][1]));
        sbc[7] = (float)(-2.0 * (Wd[1][0][1] * Wd[1][1][0] - Wd[1][0][0] * Wd[1][1][1]));
      }
    }
  } else {
    if (t == 0) {
      float2 w00 = W2[i * 4 + 0], w01 = W2[i * 4 + 1], w10 = W2[i * 4 + 2], w11 = W2[i * 4 + 3];
      sbc[0] = w00.x * w00.x + w00.y * w00.y;
      sbc[1] = w01.x * w01.x + w01.y * w01.y;
      sbc[2] = 2.f * (w00.x * w01.x + w00.y * w01.y);
      sbc[3] = -2.f * (w00.y * w01.x - w00.x * w01.y);
      sbc[4] = w10.x * w10.x + w10.y * w10.y;
      sbc[5] = w11.x * w11.x + w11.y * w11.y;
      sbc[6] = 2.f * (w10.x * w11.x + w10.y * w11.y);
      sbc[7] = -2.f * (w10.y * w11.x - w10.x * w11.y);
    }
  }

  if constexpr (DO_A) {
    __syncthreads();
    const f32x2 alp = (f32x2){sbc[0], sbc[4]}, btp = (f32x2){sbc[1], sbc[5]};
    const f32x2 gmp = (f32x2){sbc[2], sbc[6]}, dlp = (f32x2){sbc[3], sbc[7]};
    f32x2 nT[K_], dT[K_];  // {src0, src1} each
#pragma unroll
    for (int k = 0; k < K_; k++) { nT[k] = sp(0.f); dT[k] = sp(0.f); }
    float2* y0r = YdR2 + (size_t)i * JHP;
    float2* y1r = YdR2 + (size_t)(I_ + i) * JHP;
#pragma unroll 3
    for (int l = 0; l < NL; l++) {
      int j2 = t + l * 256;
      float4 x0 = x0r[j2], x1 = x1r[j2];
      f32x2 rA, rB;
      if constexpr (DO_C) {
        rA = sR[0][l][t];  // same thread wrote it in phase C -> no barrier needed
        rB = sR[1][l][t];
      } else {
        rA = sp(0.f); rB = sp(0.f);
#pragma unroll
        for (int k = 0; k < K_; k++) {
          float4 vp = V4[(size_t)k * JHP + j2];
          rA += Tp[k] * xy(vp);
          rB += Tp[k] * zw(vp);
        }
      }
      float n00a = x0.x * x0.x + x0.y * x0.y, n00b = x0.z * x0.z + x0.w * x0.w;
      float n11a = x1.x * x1.x + x1.y * x1.y, n11b = x1.z * x1.z + x1.w * x1.w;
      float crea = x0.x * x1.x + x0.y * x1.y, creb = x0.z * x1.z + x0.w * x1.w;
      float cima = x0.y * x1.x - x0.x * x1.y, cimb = x0.w * x1.z - x0.z * x1.w;
      f32x2 aA = alp * n00a + btp * n11a + gmp * crea + dlp * cima;
      f32x2 aB = alp * n00b + btp * n11b + gmp * creb + dlp * cimb;
      f32x2 ydrA = aA * (f32x2){frcp(rA.x * rA.x + EPS), frcp(rA.y * rA.y + EPS)};
      f32x2 ydrB = aB * (f32x2){frcp(rB.x * rB.x + EPS), frcp(rB.y * rB.y + EPS)};
      f32x2 rdA = (f32x2){frcp(rA.x + EPS), frcp(rA.y + EPS)};
      f32x2 rdB = (f32x2){frcp(rB.x + EPS), frcp(rB.y + EPS)};
      y0r[j2] = make_float2(ydrA.x, ydrB.x);
      y1r[j2] = make_float2(ydrA.y, ydrB.y);
      // accumulation: V loaded and consumed immediately (no vp[] array liveness)
#pragma unroll
      for (int k = 0; k < K_; k++) {
        float4 vp = V4[(size_t)k * JHP + j2];
        nT[k] += ydrA * xy(vp) + ydrB * zw(vp);
        dT[k] += rdA * xy(vp) + rdB * zw(vp);
      }
    }
#pragma unroll
    for (int k = 0; k < K_; k++) {
      float a = waveRed(nT[k].x); if (lane == 0) sred[wave][k] = a;
      float b = waveRed(dT[k].x); if (lane == 0) sred[wave][8 + k] = b;
      float c = waveRed(nT[k].y); if (lane == 0) sred[wave][16 + k] = c;
      float d = waveRed(dT[k].y); if (lane == 0) sred[wave][24 + k] = d;
    }
    __syncthreads();
    if (t < 32) sout[t] = sred[0][t] + sred[1][t] + sred[2][t] + sred[3][t];
    __syncthreads();
    if (t < 16) {
      int n = t >> 3, k = t & 7;
      float num = sout[n * 16 + k];
      float den = sout[n * 16 + 8 + k];
      float told = T[n * I_ * K_ + i * K_ + k];
      T[n * I_ * K_ + i * K_ + k] = told * sqrtf(num / (den + EPS));
    }
  }
}

// -------- pass B: partial I-reductions for the V update (j-pair packed f32x2) --------
__global__ __launch_bounds__(TJB, 4) void k_passB(const float* __restrict__ T,
                                                  const float4* __restrict__ V4,
                                                  const float2* __restrict__ YdR2,
                                                  float2* __restrict__ partial2, int iseg) {
  int t = threadIdx.x;
  int jt = blockIdx.x, s = blockIdx.y, n = blockIdx.z;
  int j2 = jt * TJB + t;  // pair index, < JHP (pads read zeros, writes guarded)
  f32x2 va2[K_];          // {v(2j), v(2j+1)} of this source
#pragma unroll
  for (int k = 0; k < K_; k++) {
    float4 vp = V4[(size_t)k * JHP + j2];
    va2[k] = (n == 0) ? (f32x2){vp.x, vp.z} : (f32x2){vp.y, vp.w};
  }
  int i0 = s * iseg, i1 = min(i0 + iseg, I_);
  const float2* yb = YdR2 + (size_t)n * I_ * JHP;
  const float* Tb = T + (size_t)n * I_ * K_;
  f32x2 nV[K_], dV[K_];
#pragma unroll
  for (int k = 0; k < K_; k++) { nV[k] = sp(0.f); dV[k] = sp(0.f); }
#pragma unroll 4
  for (int i = i0; i < i1; i++) {
    const float4* tp = (const float4*)(Tb + i * K_);
    float4 t03 = tp[0], t47 = tp[1];
    float Tn[K_] = {t03.x, t03.y, t03.z, t03.w, t47.x, t47.y, t47.z, t47.w};
    float2 yl = yb[(size_t)i * JHP + j2];
    f32x2 y = (f32x2){yl.x, yl.y};
    f32x2 R = sp(0.f);
#pragma unroll
    for (int k = 0; k < K_; k++) R += sp(Tn[k]) * va2[k];
    f32x2 rd = (f32x2){frcp(R.x + EPS), frcp(R.y + EPS)};
#pragma unroll
    for (int k = 0; k < K_; k++) {
      nV[k] += sp(Tn[k]) * y;
      dV[k] += sp(Tn[k]) * rd;
    }
  }
  if (j2 < JH) {
    size_t b0 = (size_t)((s * 2 + n) * 2 + 0) * K_ * JH;
    size_t b1 = (size_t)((s * 2 + n) * 2 + 1) * K_ * JH;
#pragma unroll
    for (int k = 0; k < K_; k++) {
      partial2[b0 + (size_t)k * JH + j2] = make_float2(nV[k].x, nV[k].y);
      partial2[b1 + (size_t)k * JH + j2] = make_float2(dV[k].x, dV[k].y);
    }
  }
}

// ---------------- finalize V: one thread per (n,k,j) ----------------
__global__ void k_finV(const float* __restrict__ partial, float* __restrict__ Vf, int nseg) {
  int idx = blockIdx.x * 256 + threadIdx.x;
  if (idx >= 2 * K_ * J_) return;
  int n = idx / (K_ * J_);
  int rem = idx - n * (K_ * J_);
  int k = rem / J_, j = rem - k * J_;
  float num = 0.f, den = 0.f;
  for (int s = 0; s < nseg; s++) {
    num += partial[((size_t)((s * 2 + n) * 2 + 0) * K_ + k) * J_ + j];
    den += partial[((size_t)((s * 2 + n) * 2 + 1) * K_ + k) * J_ + j];
  }
  float res = sqrtf(num / (den + EPS));
  Vf[((size_t)k * JP + j) * 2 + n] *= res;
}

// ---------------- final output: Y = W X, transposed to (N,J,I) ----------------
__global__ __launch_bounds__(256) void k_output(const float2* __restrict__ Xt,
                                                const float2* __restrict__ W2,
                                                float2* __restrict__ out) {
  __shared__ float2 tile[2][32][33];
  int i0 = blockIdx.x * 32, j0 = blockIdx.y * 32;
  int tx = threadIdx.x & 31, ty = threadIdx.x >> 5;
  for (int r = ty; r < 32; r += 8) {
    int i = i0 + r, j = j0 + tx;
    if (i < I_ && j < J_) {
      float2 w00 = W2[i * 4 + 0], w01 = W2[i * 4 + 1], w10 = W2[i * 4 + 2], w11 = W2[i * 4 + 3];
      float2 x0 = Xt[(size_t)i * JP + j], x1 = Xt[((size_t)I_ + i) * JP + j];
      tile[0][r][tx] = make_float2(w00.x * x0.x - w00.y * x0.y + w01.x * x1.x - w01.y * x1.y,
                                   w00.x * x0.y + w00.y * x0.x + w01.x * x1.y + w01.y * x1.x);
      tile[1][r][tx] = make_float2(w10.x * x0.x - w10.y * x0.y + w11.x * x1.x - w11.y * x1.y,
                                   w10.x * x0.y + w10.y * x0.x + w11.x * x1.y + w11.y * x1.x);
    }
  }
  __syncthreads();
  for (int r = ty; r < 32; r += 8) {
    int j = j0 + r, i = i0 + tx;
    if (i < I_ && j < J_) {
      out[((size_t)0 * J_ + j) * I_ + i] = tile[0][tx][r];
      out[((size_t)1 * J_ + j) * I_ + i] = tile[1][tx][r];
    }
  }
}

extern "C" void kernel_launch(void* const* d_in, const int* in_sizes, int n_in,
                              void* d_out, int out_size, void* d_ws, size_t ws_size,
                              hipStream_t stream) {
  const float* X = (const float*)d_in[0];
  const float* Tin = (const float*)d_in[1];
  const float* Vin = (const float*)d_in[2];

  char* ws = (char*)d_ws;
  size_t off = 0;
  auto alloc = [&](size_t bytes) {
    void* p = ws + off;
    off = (off + bytes + 255) & ~(size_t)255;
    return p;
  };
  float2* Xt = (float2*)alloc((size_t)2 * I_ * JP * sizeof(float2));
  float2* YdR2 = (float2*)alloc((size_t)2 * I_ * JHP * sizeof(float2));
  float2* V2 = (float2*)alloc((size_t)K_ * JP * sizeof(float2));
  float* T = (float*)alloc((size_t)2 * I_ * K_ * sizeof(float));
  float2* W2 = (float2*)alloc((size_t)I_ * 4 * sizeof(float2));
  size_t per_seg = (size_t)2 * 2 * K_ * J_ * sizeof(float);
  int nseg = (off + 32 * per_seg <= ws_size) ? 32 : 16;
  float* partial = (float*)alloc((size_t)nseg * per_seg);
  int iseg = (I_ + nseg - 1) / nseg;
  (void)in_sizes; (void)n_in; (void)out_size;

  const float4* Xt4 = (const float4*)Xt;
  const float4* V4 = (const float4*)V2;

  k_init<<<(I_ * K_ * 2 + 255) / 256, 256, 0, stream>>>(Tin, Vin, T, V2, W2);
  dim3 tg((I_ + 31) / 32, JP / 32, 2);
  k_transpose<<<tg, 256, 0, stream>>>((const float2*)X, Xt);

  // A(0)
  k_CA<false, true><<<I_, 256, 0, stream>>>(Xt4, W2, T, V4, YdR2);
  for (int it = 0; it < NITER; it++) {
    k_passB<<<dim3(NJTP, nseg, 2), TJB, 0, stream>>>(T, V4, YdR2, (float2*)partial, iseg);
    k_finV<<<(2 * K_ * J_ + 255) / 256, 256, 0, stream>>>(partial, (float*)V2, nseg);
    if (it < NITER - 1) {
      k_CA<true, true><<<I_, 256, 0, stream>>>(Xt4, W2, T, V4, YdR2);
    } else {
      k_CA<true, false><<<I_, 256, 0, stream>>>(Xt4, W2, T, V4, YdR2);
    }
  }
  dim3 og((I_ + 31) / 32, (J_ + 31) / 32);
  k_output<<<og, 256, 0, stream>>>(Xt, W2, (float2*)d_out);
}

// Round 10
// 3372.933 us; speedup vs baseline: 1.0442x; 1.0442x over previous
//
#include <hip/hip_runtime.h>

#define DEVINL __device__ __forceinline__

constexpr int J_ = 3000;   // frames
constexpr int I_ = 2049;   // freq bins
constexpr int K_ = 8;      // NMF bases
constexpr int NITER = 30;
constexpr float EPS = 1e-20f;  // NMF_EPS == IP_EPS
constexpr int JH = 1500;       // real j-pairs per row
constexpr int JHP = 1536;      // padded j-pairs (6*256)
constexpr int JP = 2 * JHP;    // padded j count = 3072
constexpr int NL = JHP / 256;  // 6 uniform loop iterations
constexpr int TJB = 256;
constexpr int NJTP = JHP / TJB;  // 6
constexpr int IBLK = 1025;       // k_CA grid: block b handles rows b and b+1025

typedef float f32x2 __attribute__((ext_vector_type(2)));

DEVINL float waveRed(float v) {
#pragma unroll
  for (int off = 32; off > 0; off >>= 1) v += __shfl_xor(v, off, 64);
  return v;
}

DEVINL float frcp(float x) { return __builtin_amdgcn_rcpf(x); }  // ~1 ulp
DEVINL f32x2 sp(float s) { return (f32x2){s, s}; }
DEVINL f32x2 xy(float4 v) { return (f32x2){v.x, v.y}; }
DEVINL f32x2 zw(float4 v) { return (f32x2){v.z, v.w}; }

// ---------------- init: T -> (n,i,k); V copy (padded, zero-fill); W = identity ----------------
__global__ void k_init(const float* __restrict__ Tin, const float* __restrict__ Vin,
                       float* __restrict__ T, float2* __restrict__ V2, float2* __restrict__ W2) {
  int idx = blockIdx.x * 256 + threadIdx.x;
  if (idx < I_ * K_ * 2) {
    int n = idx & 1, rem = idx >> 1;  // idx = (i*K + k)*2 + n
    int k = rem & 7, i = rem >> 3;
    T[n * I_ * K_ + i * K_ + k] = Tin[idx];
  }
  if (idx < K_ * JP) {
    int k = idx / JP, j = idx - k * JP;
    float2 v = (j < J_) ? ((const float2*)Vin)[k * J_ + j] : make_float2(0.f, 0.f);
    V2[k * JP + j] = v;
  }
  if (idx < I_) {
    W2[idx * 4 + 0] = make_float2(1.f, 0.f);
    W2[idx * 4 + 1] = make_float2(0.f, 0.f);
    W2[idx * 4 + 2] = make_float2(0.f, 0.f);
    W2[idx * 4 + 3] = make_float2(1.f, 0.f);
  }
}

// ------- transpose X (M,J,I) cplx -> Xt (M,I,JP) cplx, zero-padding j in [J_,JP) -------
__global__ __launch_bounds__(256) void k_transpose(const float2* __restrict__ X, float2* __restrict__ Xt) {
  __shared__ float2 tile[32][33];
  int m = blockIdx.z;
  int i0 = blockIdx.x * 32, j0 = blockIdx.y * 32;
  int tx = threadIdx.x & 31, ty = threadIdx.x >> 5;
  for (int r = ty; r < 32; r += 8) {
    int j = j0 + r, i = i0 + tx;
    tile[r][tx] = (i < I_ && j < J_) ? X[((size_t)m * J_ + j) * I_ + i] : make_float2(0.f, 0.f);
  }
  __syncthreads();
  for (int r = ty; r < 32; r += 8) {
    int i = i0 + r, j = j0 + tx;
    if (i < I_) Xt[((size_t)m * I_ + i) * JP + j] = tile[tx][r];
  }
}

DEVINL void ip_solve(const float* sout8, float2* W2, int irow, float* sbc8, bool fill_sbc) {
  const double Jinv = 1.0 / (double)J_;
  double D[2][4];
#pragma unroll
  for (int s2 = 0; s2 < 2; s2++) {
    D[s2][0] = (double)sout8[s2 * 4 + 0] * Jinv + (double)EPS;
    D[s2][1] = (double)sout8[s2 * 4 + 1] * Jinv + (double)EPS;
    D[s2][2] = (double)sout8[s2 * 4 + 2] * Jinv;
    D[s2][3] = (double)sout8[s2 * 4 + 3] * Jinv;
  }
  double Wd[2][2][2];
#pragma unroll
  for (int r = 0; r < 2; r++)
#pragma unroll
    for (int c = 0; c < 2; c++) {
      float2 w = W2[irow * 4 + r * 2 + c];
      Wd[r][c][0] = w.x;
      Wd[r][c][1] = w.y;
    }
  for (int n2 = 0; n2 < 2; n2++) {
    double d00 = D[n2][0], d11 = D[n2][1], dre = D[n2][2], dim = D[n2][3];
    double A[2][2][2];
#pragma unroll
    for (int r = 0; r < 2; r++) {
      A[r][0][0] = Wd[r][0][0] * d00 + (Wd[r][1][0] * dre + Wd[r][1][1] * dim);
      A[r][0][1] = Wd[r][0][1] * d00 + (Wd[r][1][1] * dre - Wd[r][1][0] * dim);
      A[r][1][0] = Wd[r][1][0] * d11 + (Wd[r][0][0] * dre - Wd[r][0][1] * dim);
      A[r][1][1] = Wd[r][1][1] * d11 + (Wd[r][0][1] * dre + Wd[r][0][0] * dim);
    }
    double detre = A[0][0][0] * A[1][1][0] - A[0][0][1] * A[1][1][1]
                 - (A[0][1][0] * A[1][0][0] - A[0][1][1] * A[1][0][1]);
    double detim = A[0][0][0] * A[1][1][1] + A[0][0][1] * A[1][1][0]
                 - (A[0][1][0] * A[1][0][1] + A[0][1][1] * A[1][0][0]);
    double b0re, b0im, b1re, b1im;
    if (n2 == 0) { b0re = A[1][1][0]; b0im = A[1][1][1]; b1re = -A[1][0][0]; b1im = -A[1][0][1]; }
    else         { b0re = -A[0][1][0]; b0im = -A[0][1][1]; b1re = A[0][0][0]; b1im = A[0][0][1]; }
    double dmag = detre * detre + detim * detim;
    double t0re = (b0re * detre + b0im * detim) / dmag, t0im = (b0im * detre - b0re * detim) / dmag;
    double t1re = (b1re * detre + b1im * detim) / dmag, t1im = (b1im * detre - b1re * detim) / dmag;
    double pre = t0re * t1re + t0im * t1im, pim = t0re * t1im - t0im * t1re;
    double quad = d00 * (t0re * t0re + t0im * t0im) + d11 * (t1re * t1re + t1im * t1im)
                + 2.0 * (dre * pre - dim * pim);
    double denom = sqrt(quad + (double)EPS);
    double w0re = t0re / denom, w0im = -t0im / denom;
    double w1re = t1re / denom, w1im = -t1im / denom;
    Wd[n2][0][0] = w0re; Wd[n2][0][1] = w0im;
    Wd[n2][1][0] = w1re; Wd[n2][1][1] = w1im;
    W2[irow * 4 + n2 * 2 + 0] = make_float2((float)w0re, (float)w0im);
    W2[irow * 4 + n2 * 2 + 1] = make_float2((float)w1re, (float)w1im);
  }
  if (fill_sbc) {
    sbc8[0] = (float)(Wd[0][0][0] * Wd[0][0][0] + Wd[0][0][1] * Wd[0][0][1]);
    sbc8[1] = (float)(Wd[0][1][0] * Wd[0][1][0] + Wd[0][1][1] * Wd[0][1][1]);
    sbc8[2] = (float)(2.0 * (Wd[0][0][0] * Wd[0][1][0] + Wd[0][0][1] * Wd[0][1][1]));
    sbc8[3] = (float)(-2.0 * (Wd[0][0][1] * Wd[0][1][0] - Wd[0][0][0] * Wd[0][1][1]));
    sbc8[4] = (float)(Wd[1][0][0] * Wd[1][0][0] + Wd[1][0][1] * Wd[1][0][1]);
    sbc8[5] = (float)(Wd[1][1][0] * Wd[1][1][0] + Wd[1][1][1] * Wd[1][1][1]);
    sbc8[6] = (float)(2.0 * (Wd[1][0][0] * Wd[1][1][0] + Wd[1][0][1] * Wd[1][1][1]));
    sbc8[7] = (float)(-2.0 * (Wd[1][0][1] * Wd[1][1][0] - Wd[1][0][0] * Wd[1][1][1]));
  }
}

// ============ fused kernel: [C(t): D + IP -> W_new] + [A(t+1): YdR + T update] ============
// TWO freq rows per block (i0 = b, i1 = b+1025): phase C loads V once per window for both
// rows' R-dots (V L2 traffic halved); R carried to phase A via LDS; phase A row-sequential
// (keeps nT/dT at 32 VGPR). Per-row math identical to the 1-row version (bitwise).
template <bool DO_C, bool DO_A>
__global__ __launch_bounds__(256, 4) void k_CA(const float4* __restrict__ Xt4,  // (2,I,JHP)
                                               float2* __restrict__ W2,
                                               float* __restrict__ T,           // (2,I,K)
                                               const float4* __restrict__ V4,   // (K,JHP) {v0a,v1a,v0b,v1b}
                                               float2* __restrict__ YdR2) {     // (2,I,JHP)
  const int t = threadIdx.x;
  const int wave = t >> 6, lane = t & 63;
  const int i0 = blockIdx.x;
  const int i1raw = blockIdx.x + IBLK;
  const bool act1 = (i1raw < I_);
  const int i1 = act1 ? i1raw : i0;  // clamped for reads; writes guarded

  f32x2 Tp0[K_], Tp1[K_];
#pragma unroll
  for (int k = 0; k < K_; k++) {
    Tp0[k] = (f32x2){T[i0 * K_ + k], T[I_ * K_ + i0 * K_ + k]};
    Tp1[k] = (f32x2){T[i1 * K_ + k], T[I_ * K_ + i1 * K_ + k]};
  }

  __shared__ f32x2 sR[2][2][NL][256];  // [row][a/b][window][thread], 48 KB
  __shared__ float sred[4][32];
  __shared__ float soutC[2][8];
  __shared__ float soutA[32];
  __shared__ float sbc[2][8];

  if constexpr (DO_C) {
    const float4* x0r0 = Xt4 + (size_t)i0 * JHP;
    const float4* x1r0 = Xt4 + (size_t)(I_ + i0) * JHP;
    const float4* x0r1 = Xt4 + (size_t)i1 * JHP;
    const float4* x1r1 = Xt4 + (size_t)(I_ + i1) * JHP;
    f32x2 an00_0 = sp(0.f), an11_0 = sp(0.f), acre_0 = sp(0.f), acim_0 = sp(0.f);
    f32x2 an00_1 = sp(0.f), an11_1 = sp(0.f), acre_1 = sp(0.f), acim_1 = sp(0.f);
#pragma unroll 1
    for (int l = 0; l < NL; l++) {
      int j2 = t + l * 256;
      float4 x0a = x0r0[j2], x1a = x1r0[j2];
      float4 x0b = x0r1[j2], x1b = x1r1[j2];
      f32x2 rA0 = sp(0.f), rB0 = sp(0.f), rA1 = sp(0.f), rB1 = sp(0.f);
#pragma unroll
      for (int k = 0; k < K_; k++) {
        float4 vp = V4[(size_t)k * JHP + j2];  // one V load serves BOTH rows
        rA0 += Tp0[k] * xy(vp); rB0 += Tp0[k] * zw(vp);
        rA1 += Tp1[k] * xy(vp); rB1 += Tp1[k] * zw(vp);
      }
      if constexpr (DO_A) {
        sR[0][0][l][t] = rA0; sR[0][1][l][t] = rB0;
        sR[1][0][l][t] = rA1; sR[1][1][l][t] = rB1;
      }
      {  // row 0
        f32x2 iA = (f32x2){frcp(rA0.x + EPS), frcp(rA0.y + EPS)};
        f32x2 iB = (f32x2){frcp(rB0.x + EPS), frcp(rB0.y + EPS)};
        float n00a = x0a.x * x0a.x + x0a.y * x0a.y, n00b = x0a.z * x0a.z + x0a.w * x0a.w;
        float n11a = x1a.x * x1a.x + x1a.y * x1a.y, n11b = x1a.z * x1a.z + x1a.w * x1a.w;
        float crea = x0a.x * x1a.x + x0a.y * x1a.y, creb = x0a.z * x1a.z + x0a.w * x1a.w;
        float cima = x0a.y * x1a.x - x0a.x * x1a.y, cimb = x0a.w * x1a.z - x0a.z * x1a.w;
        an00_0 += sp(n00a) * iA + sp(n00b) * iB;
        an11_0 += sp(n11a) * iA + sp(n11b) * iB;
        acre_0 += sp(crea) * iA + sp(creb) * iB;
        acim_0 += sp(cima) * iA + sp(cimb) * iB;
      }
      {  // row 1
        f32x2 iA = (f32x2){frcp(rA1.x + EPS), frcp(rA1.y + EPS)};
        f32x2 iB = (f32x2){frcp(rB1.x + EPS), frcp(rB1.y + EPS)};
        float n00a = x0b.x * x0b.x + x0b.y * x0b.y, n00b = x0b.z * x0b.z + x0b.w * x0b.w;
        float n11a = x1b.x * x1b.x + x1b.y * x1b.y, n11b = x1b.z * x1b.z + x1b.w * x1b.w;
        float crea = x0b.x * x1b.x + x0b.y * x1b.y, creb = x0b.z * x1b.z + x0b.w * x1b.w;
        float cima = x0b.y * x1b.x - x0b.x * x1b.y, cimb = x0b.w * x1b.z - x0b.z * x1b.w;
        an00_1 += sp(n00a) * iA + sp(n00b) * iB;
        an11_1 += sp(n11a) * iA + sp(n11b) * iB;
        acre_1 += sp(crea) * iA + sp(creb) * iB;
        acim_1 += sp(cima) * iA + sp(cimb) * iB;
      }
    }
    float vals[16] = {an00_0.x, an11_0.x, acre_0.x, acim_0.x, an00_0.y, an11_0.y, acre_0.y, acim_0.y,
                      an00_1.x, an11_1.x, acre_1.x, acim_1.x, an00_1.y, an11_1.y, acre_1.y, acim_1.y};
#pragma unroll
    for (int q = 0; q < 16; q++) {
      float v = waveRed(vals[q]);
      if (lane == 0) sred[wave][q] = v;
    }
    __syncthreads();
    if (t < 16) {
      int r = t >> 3, q = t & 7;
      soutC[r][q] = sred[0][t] + sred[1][t] + sred[2][t] + sred[3][t];
    }
    __syncthreads();
    if (t == 0) ip_solve(soutC[0], W2, i0, sbc[0], DO_A);
    if (t == 64 && act1) ip_solve(soutC[1], W2, i1, sbc[1], DO_A);
  } else {
    if (t == 0 || (t == 64 && act1)) {
      int r = t >> 6;
      int irow = r ? i1 : i0;
      float2 w00 = W2[irow * 4 + 0], w01 = W2[irow * 4 + 1], w10 = W2[irow * 4 + 2], w11 = W2[irow * 4 + 3];
      sbc[r][0] = w00.x * w00.x + w00.y * w00.y;
      sbc[r][1] = w01.x * w01.x + w01.y * w01.y;
      sbc[r][2] = 2.f * (w00.x * w01.x + w00.y * w01.y);
      sbc[r][3] = -2.f * (w00.y * w01.x - w00.x * w01.y);
      sbc[r][4] = w10.x * w10.x + w10.y * w10.y;
      sbc[r][5] = w11.x * w11.x + w11.y * w11.y;
      sbc[r][6] = 2.f * (w10.x * w11.x + w10.y * w11.y);
      sbc[r][7] = -2.f * (w10.y * w11.x - w10.x * w11.y);
    }
  }

  if constexpr (DO_A) {
    __syncthreads();
#pragma unroll
    for (int r = 0; r < 2; r++) {  // unrolled -> all r-indexed accesses static
      const bool act = (r == 0) || act1;
      const int irow = r ? i1 : i0;
      const f32x2 alp = (f32x2){sbc[r][0], sbc[r][4]}, btp = (f32x2){sbc[r][1], sbc[r][5]};
      const f32x2 gmp = (f32x2){sbc[r][2], sbc[r][6]}, dlp = (f32x2){sbc[r][3], sbc[r][7]};
      const float4* xr0 = Xt4 + (size_t)irow * JHP;
      const float4* xr1 = Xt4 + (size_t)(I_ + irow) * JHP;
      float2* y0r = YdR2 + (size_t)irow * JHP;
      float2* y1r = YdR2 + (size_t)(I_ + irow) * JHP;
      f32x2 nT[K_], dT[K_];
#pragma unroll
      for (int k = 0; k < K_; k++) { nT[k] = sp(0.f); dT[k] = sp(0.f); }
#pragma unroll 1
      for (int l = 0; l < NL; l++) {
        int j2 = t + l * 256;
        float4 x0 = xr0[j2], x1 = xr1[j2];
        f32x2 rA, rB;
        if constexpr (DO_C) {
          rA = sR[r][0][l][t];  // same thread wrote it in phase C
          rB = sR[r][1][l][t];
        } else {
          rA = sp(0.f); rB = sp(0.f);
#pragma unroll
          for (int k = 0; k < K_; k++) {
            float4 vp = V4[(size_t)k * JHP + j2];
            if (r == 0) { rA += Tp0[k] * xy(vp); rB += Tp0[k] * zw(vp); }
            else        { rA += Tp1[k] * xy(vp); rB += Tp1[k] * zw(vp); }
          }
        }
        float n00a = x0.x * x0.x + x0.y * x0.y, n00b = x0.z * x0.z + x0.w * x0.w;
        float n11a = x1.x * x1.x + x1.y * x1.y, n11b = x1.z * x1.z + x1.w * x1.w;
        float crea = x0.x * x1.x + x0.y * x1.y, creb = x0.z * x1.z + x0.w * x1.w;
        float cima = x0.y * x1.x - x0.x * x1.y, cimb = x0.w * x1.z - x0.z * x1.w;
        f32x2 aA = alp * n00a + btp * n11a + gmp * crea + dlp * cima;
        f32x2 aB = alp * n00b + btp * n11b + gmp * creb + dlp * cimb;
        f32x2 ydrA = aA * (f32x2){frcp(rA.x * rA.x + EPS), frcp(rA.y * rA.y + EPS)};
        f32x2 ydrB = aB * (f32x2){frcp(rB.x * rB.x + EPS), frcp(rB.y * rB.y + EPS)};
        f32x2 rdA = (f32x2){frcp(rA.x + EPS), frcp(rA.y + EPS)};
        f32x2 rdB = (f32x2){frcp(rB.x + EPS), frcp(rB.y + EPS)};
        if (act) {
          y0r[j2] = make_float2(ydrA.x, ydrB.x);
          y1r[j2] = make_float2(ydrA.y, ydrB.y);
        }
#pragma unroll
        for (int k = 0; k < K_; k++) {
          float4 vp = V4[(size_t)k * JHP + j2];
          nT[k] += ydrA * xy(vp) + ydrB * zw(vp);
          dT[k] += rdA * xy(vp) + rdB * zw(vp);
        }
      }
#pragma unroll
      for (int k = 0; k < K_; k++) {
        float a = waveRed(nT[k].x); if (lane == 0) sred[wave][k] = a;
        float b = waveRed(dT[k].x); if (lane == 0) sred[wave][8 + k] = b;
        float c = waveRed(nT[k].y); if (lane == 0) sred[wave][16 + k] = c;
        float d = waveRed(dT[k].y); if (lane == 0) sred[wave][24 + k] = d;
      }
      __syncthreads();
      if (t < 32) soutA[t] = sred[0][t] + sred[1][t] + sred[2][t] + sred[3][t];
      __syncthreads();
      if (t < 16 && act) {
        int n = t >> 3, k = t & 7;
        float num = soutA[n * 16 + k];
        float den = soutA[n * 16 + 8 + k];
        float told = T[n * I_ * K_ + irow * K_ + k];
        T[n * I_ * K_ + irow * K_ + k] = told * sqrtf(num / (den + EPS));
      }
    }
  }
}

// -------- pass B: partial I-reductions for the V update (j-pair packed f32x2) --------
__global__ __launch_bounds__(TJB, 4) void k_passB(const float* __restrict__ T,
                                                  const float4* __restrict__ V4,
                                                  const float2* __restrict__ YdR2,
                                                  float2* __restrict__ partial2, int iseg) {
  int t = threadIdx.x;
  int jt = blockIdx.x, s = blockIdx.y, n = blockIdx.z;
  int j2 = jt * TJB + t;  // pair index, < JHP (pads read zeros, writes guarded)
  f32x2 va2[K_];          // {v(2j), v(2j+1)} of this source
#pragma unroll
  for (int k = 0; k < K_; k++) {
    float4 vp = V4[(size_t)k * JHP + j2];
    va2[k] = (n == 0) ? (f32x2){vp.x, vp.z} : (f32x2){vp.y, vp.w};
  }
  int i0 = s * iseg, i1 = min(i0 + iseg, I_);
  const float2* yb = YdR2 + (size_t)n * I_ * JHP;
  const float* Tb = T + (size_t)n * I_ * K_;
  f32x2 nV[K_], dV[K_];
#pragma unroll
  for (int k = 0; k < K_; k++) { nV[k] = sp(0.f); dV[k] = sp(0.f); }
#pragma unroll 4
  for (int i = i0; i < i1; i++) {
    const float4* tp = (const float4*)(Tb + i * K_);
    float4 t03 = tp[0], t47 = tp[1];
    float Tn[K_] = {t03.x, t03.y, t03.z, t03.w, t47.x, t47.y, t47.z, t47.w};
    float2 yl = yb[(size_t)i * JHP + j2];
    f32x2 y = (f32x2){yl.x, yl.y};
    f32x2 R = sp(0.f);
#pragma unroll
    for (int k = 0; k < K_; k++) R += sp(Tn[k]) * va2[k];
    f32x2 rd = (f32x2){frcp(R.x + EPS), frcp(R.y + EPS)};
#pragma unroll
    for (int k = 0; k < K_; k++) {
      nV[k] += sp(Tn[k]) * y;
      dV[k] += sp(Tn[k]) * rd;
    }
  }
  if (j2 < JH) {
    size_t b0 = (size_t)((s * 2 + n) * 2 + 0) * K_ * JH;
    size_t b1 = (size_t)((s * 2 + n) * 2 + 1) * K_ * JH;
#pragma unroll
    for (int k = 0; k < K_; k++) {
      partial2[b0 + (size_t)k * JH + j2] = make_float2(nV[k].x, nV[k].y);
      partial2[b1 + (size_t)k * JH + j2] = make_float2(dV[k].x, dV[k].y);
    }
  }
}

// ---------------- finalize V: one thread per (n,k,j) ----------------
__global__ void k_finV(const float* __restrict__ partial, float* __restrict__ Vf, int nseg) {
  int idx = blockIdx.x * 256 + threadIdx.x;
  if (idx >= 2 * K_ * J_) return;
  int n = idx / (K_ * J_);
  int rem = idx - n * (K_ * J_);
  int k = rem / J_, j = rem - k * J_;
  float num = 0.f, den = 0.f;
  for (int s = 0; s < nseg; s++) {
    num += partial[((size_t)((s * 2 + n) * 2 + 0) * K_ + k) * J_ + j];
    den += partial[((size_t)((s * 2 + n) * 2 + 1) * K_ + k) * J_ + j];
  }
  float res = sqrtf(num / (den + EPS));
  Vf[((size_t)k * JP + j) * 2 + n] *= res;
}

// ---------------- final output: Y = W X, transposed to (N,J,I) ----------------
__global__ __launch_bounds__(256) void k_output(const float2* __restrict__ Xt,
                                                const float2* __restrict__ W2,
                                                float2* __restrict__ out) {
  __shared__ float2 tile[2][32][33];
  int i0 = blockIdx.x * 32, j0 = blockIdx.y * 32;
  int tx = threadIdx.x & 31, ty = threadIdx.x >> 5;
  for (int r = ty; r < 32; r += 8) {
    int i = i0 + r, j = j0 + tx;
    if (i < I_ && j < J_) {
      float2 w00 = W2[i * 4 + 0], w01 = W2[i * 4 + 1], w10 = W2[i * 4 + 2], w11 = W2[i * 4 + 3];
      float2 x0 = Xt[(size_t)i * JP + j], x1 = Xt[((size_t)I_ + i) * JP + j];
      tile[0][r][tx] = make_float2(w00.x * x0.x - w00.y * x0.y + w01.x * x1.x - w01.y * x1.y,
                                   w00.x * x0.y + w00.y * x0.x + w01.x * x1.y + w01.y * x1.x);
      tile[1][r][tx] = make_float2(w10.x * x0.x - w10.y * x0.y + w11.x * x1.x - w11.y * x1.y,
                                   w10.x * x0.y + w10.y * x0.x + w11.x * x1.y + w11.y * x1.x);
    }
  }
  __syncthreads();
  for (int r = ty; r < 32; r += 8) {
    int j = j0 + r, i = i0 + tx;
    if (i < I_ && j < J_) {
      out[((size_t)0 * J_ + j) * I_ + i] = tile[0][tx][r];
      out[((size_t)1 * J_ + j) * I_ + i] = tile[1][tx][r];
    }
  }
}

extern "C" void kernel_launch(void* const* d_in, const int* in_sizes, int n_in,
                              void* d_out, int out_size, void* d_ws, size_t ws_size,
                              hipStream_t stream) {
  const float* X = (const float*)d_in[0];
  const float* Tin = (const float*)d_in[1];
  const float* Vin = (const float*)d_in[2];

  char* ws = (char*)d_ws;
  size_t off = 0;
  auto alloc = [&](size_t bytes) {
    void* p = ws + off;
    off = (off + bytes + 255) & ~(size_t)255;
    return p;
  };
  float2* Xt = (float2*)alloc((size_t)2 * I_ * JP * sizeof(float2));
  float2* YdR2 = (float2*)alloc((size_t)2 * I_ * JHP * sizeof(float2));
  float2* V2 = (float2*)alloc((size_t)K_ * JP * sizeof(float2));
  float* T = (float*)alloc((size_t)2 * I_ * K_ * sizeof(float));
  float2* W2 = (float2*)alloc((size_t)I_ * 4 * sizeof(float2));
  size_t per_seg = (size_t)2 * 2 * K_ * J_ * sizeof(float);
  int nseg = (off + 64 * per_seg <= ws_size) ? 64 : ((off + 32 * per_seg <= ws_size) ? 32 : 16);
  float* partial = (float*)alloc((size_t)nseg * per_seg);
  int iseg = (I_ + nseg - 1) / nseg;
  (void)in_sizes; (void)n_in; (void)out_size;

  const float4* Xt4 = (const float4*)Xt;
  const float4* V4 = (const float4*)V2;

  k_init<<<(I_ * K_ * 2 + 255) / 256, 256, 0, stream>>>(Tin, Vin, T, V2, W2);
  dim3 tg((I_ + 31) / 32, JP / 32, 2);
  k_transpose<<<tg, 256, 0, stream>>>((const float2*)X, Xt);

  // A(0)
  k_CA<false, true><<<IBLK, 256, 0, stream>>>(Xt4, W2, T, V4, YdR2);
  for (int it = 0; it < NITER; it++) {
    k_passB<<<dim3(NJTP, nseg, 2), TJB, 0, stream>>>(T, V4, YdR2, (float2*)partial, iseg);
    k_finV<<<(2 * K_ * J_ + 255) / 256, 256, 0, stream>>>(partial, (float*)V2, nseg);
    if (it < NITER - 1) {
      k_CA<true, true><<<IBLK, 256, 0, stream>>>(Xt4, W2, T, V4, YdR2);
    } else {
      k_CA<true, false><<<IBLK, 256, 0, stream>>>(Xt4, W2, T, V4, YdR2);
    }
  }
  dim3 og((I_ + 31) / 32, (J_ + 31) / 32);
  k_output<<<og, 256, 0, stream>>>(Xt, W2, (float2*)d_out);
}

// Round 11
// 3131.364 us; speedup vs baseline: 1.1247x; 1.0771x over previous
//
#include <hip/hip_runtime.h>

#define DEVINL __device__ __forceinline__

constexpr int J_ = 3000;   // frames
constexpr int I_ = 2049;   // freq bins
constexpr int K_ = 8;      // NMF bases
constexpr int NITER = 30;
constexpr float EPS = 1e-20f;  // NMF_EPS == IP_EPS
constexpr int JH = 1500;       // real j-pairs per row
constexpr int JHP = 1536;      // padded j-pairs (6*256)
constexpr int JP = 2 * JHP;    // padded j count = 3072
constexpr int NL = JHP / 256;  // 6 uniform loop iterations
constexpr int TJB = 256;
constexpr int NJTP = JHP / TJB;  // 6

typedef float f32x2 __attribute__((ext_vector_type(2)));

DEVINL float waveRed(float v) {
#pragma unroll
  for (int off = 32; off > 0; off >>= 1) v += __shfl_xor(v, off, 64);
  return v;
}

DEVINL float frcp(float x) { return __builtin_amdgcn_rcpf(x); }  // ~1 ulp
DEVINL f32x2 sp(float s) { return (f32x2){s, s}; }
DEVINL f32x2 xy(float4 v) { return (f32x2){v.x, v.y}; }
DEVINL f32x2 zw(float4 v) { return (f32x2){v.z, v.w}; }

// ---------------- init: T -> (n,i,k); V copy (padded, zero-fill); W = identity ----------------
__global__ void k_init(const float* __restrict__ Tin, const float* __restrict__ Vin,
                       float* __restrict__ T, float2* __restrict__ V2, float2* __restrict__ W2) {
  int idx = blockIdx.x * 256 + threadIdx.x;
  if (idx < I_ * K_ * 2) {
    int n = idx & 1, rem = idx >> 1;  // idx = (i*K + k)*2 + n
    int k = rem & 7, i = rem >> 3;
    T[n * I_ * K_ + i * K_ + k] = Tin[idx];
  }
  if (idx < K_ * JP) {
    int k = idx / JP, j = idx - k * JP;
    float2 v = (j < J_) ? ((const float2*)Vin)[k * J_ + j] : make_float2(0.f, 0.f);
    V2[k * JP + j] = v;
  }
  if (idx < I_) {
    W2[idx * 4 + 0] = make_float2(1.f, 0.f);
    W2[idx * 4 + 1] = make_float2(0.f, 0.f);
    W2[idx * 4 + 2] = make_float2(0.f, 0.f);
    W2[idx * 4 + 3] = make_float2(1.f, 0.f);
  }
}

// ------- transpose X (M,J,I) cplx -> Xt (M,I,JP) cplx, zero-padding j in [J_,JP) -------
__global__ __launch_bounds__(256) void k_transpose(const float2* __restrict__ X, float2* __restrict__ Xt) {
  __shared__ float2 tile[32][33];
  int m = blockIdx.z;
  int i0 = blockIdx.x * 32, j0 = blockIdx.y * 32;
  int tx = threadIdx.x & 31, ty = threadIdx.x >> 5;
  for (int r = ty; r < 32; r += 8) {
    int j = j0 + r, i = i0 + tx;
    tile[r][tx] = (i < I_ && j < J_) ? X[((size_t)m * J_ + j) * I_ + i] : make_float2(0.f, 0.f);
  }
  __syncthreads();
  for (int r = ty; r < 32; r += 8) {
    int i = i0 + r, j = j0 + tx;
    if (i < I_) Xt[((size_t)m * I_ + i) * JP + j] = tile[tx][r];
  }
}

// ============ fused kernel: [C(t): D + IP -> W_new] + [A(t+1): YdR + T update] ============
// Best-measured configuration (round 5): source-packed f32x2 math, phase A recomputes R
// (L2-hot), C-loop unroll 2 / A-loop unroll 1, VGPR ~60, 256 threads, no cross-phase carry.
template <bool DO_C, bool DO_A>
__global__ __launch_bounds__(256, 4) void k_CA(const float4* __restrict__ Xt4,  // (2,I,JHP)
                                               float2* __restrict__ W2,
                                               float* __restrict__ T,           // (2,I,K)
                                               const float4* __restrict__ V4,   // (K,JHP) {v0a,v1a,v0b,v1b}
                                               float2* __restrict__ YdR2) {     // (2,I,JHP)
  const int i = blockIdx.x, t = threadIdx.x;
  const int wave = t >> 6, lane = t & 63;
  f32x2 Tp[K_];  // {T0[k], T1[k]}
#pragma unroll
  for (int k = 0; k < K_; k++) {
    Tp[k] = (f32x2){T[i * K_ + k], T[I_ * K_ + i * K_ + k]};
  }
  const float4* x0r = Xt4 + (size_t)i * JHP;
  const float4* x1r = Xt4 + (size_t)(I_ + i) * JHP;

  __shared__ float sred[4][32];
  __shared__ float sout[32];
  __shared__ float sbc[8];  // alpha,beta,gamma,delta per source

  if constexpr (DO_C) {
    f32x2 an00 = sp(0.f), an11 = sp(0.f), acre = sp(0.f), acim = sp(0.f);  // {src0,src1}
#pragma unroll 2
    for (int l = 0; l < NL; l++) {
      int j2 = t + l * 256;
      float4 x0 = x0r[j2], x1 = x1r[j2];
      f32x2 rA = sp(0.f), rB = sp(0.f);
#pragma unroll
      for (int k = 0; k < K_; k++) {
        float4 vp = V4[(size_t)k * JHP + j2];
        rA += Tp[k] * xy(vp);
        rB += Tp[k] * zw(vp);
      }
      f32x2 iA = (f32x2){frcp(rA.x + EPS), frcp(rA.y + EPS)};
      f32x2 iB = (f32x2){frcp(rB.x + EPS), frcp(rB.y + EPS)};
      float n00a = x0.x * x0.x + x0.y * x0.y, n00b = x0.z * x0.z + x0.w * x0.w;
      float n11a = x1.x * x1.x + x1.y * x1.y, n11b = x1.z * x1.z + x1.w * x1.w;
      float crea = x0.x * x1.x + x0.y * x1.y, creb = x0.z * x1.z + x0.w * x1.w;
      float cima = x0.y * x1.x - x0.x * x1.y, cimb = x0.w * x1.z - x0.z * x1.w;
      an00 += sp(n00a) * iA + sp(n00b) * iB;
      an11 += sp(n11a) * iA + sp(n11b) * iB;
      acre += sp(crea) * iA + sp(creb) * iB;
      acim += sp(cima) * iA + sp(cimb) * iB;
    }
    float vals[8] = {an00.x, an11.x, acre.x, acim.x, an00.y, an11.y, acre.y, acim.y};
#pragma unroll
    for (int q = 0; q < 8; q++) {
      float v = waveRed(vals[q]);
      if (lane == 0) sred[wave][q] = v;
    }
    __syncthreads();
    if (t < 8) sout[t] = sred[0][t] + sred[1][t] + sred[2][t] + sred[3][t];
    __syncthreads();
    if (t == 0) {
      const double Jinv = 1.0 / (double)J_;
      double D[2][4];
#pragma unroll
      for (int s2 = 0; s2 < 2; s2++) {
        D[s2][0] = (double)sout[s2 * 4 + 0] * Jinv + (double)EPS;
        D[s2][1] = (double)sout[s2 * 4 + 1] * Jinv + (double)EPS;
        D[s2][2] = (double)sout[s2 * 4 + 2] * Jinv;
        D[s2][3] = (double)sout[s2 * 4 + 3] * Jinv;
      }
      double Wd[2][2][2];
#pragma unroll
      for (int r = 0; r < 2; r++)
#pragma unroll
        for (int c = 0; c < 2; c++) {
          float2 w = W2[i * 4 + r * 2 + c];
          Wd[r][c][0] = w.x;
          Wd[r][c][1] = w.y;
        }
      for (int n2 = 0; n2 < 2; n2++) {
        double d00 = D[n2][0], d11 = D[n2][1], dre = D[n2][2], dim = D[n2][3];
        double A[2][2][2];
#pragma unroll
        for (int r = 0; r < 2; r++) {
          A[r][0][0] = Wd[r][0][0] * d00 + (Wd[r][1][0] * dre + Wd[r][1][1] * dim);
          A[r][0][1] = Wd[r][0][1] * d00 + (Wd[r][1][1] * dre - Wd[r][1][0] * dim);
          A[r][1][0] = Wd[r][1][0] * d11 + (Wd[r][0][0] * dre - Wd[r][0][1] * dim);
          A[r][1][1] = Wd[r][1][1] * d11 + (Wd[r][0][1] * dre + Wd[r][0][0] * dim);
        }
        double detre = A[0][0][0] * A[1][1][0] - A[0][0][1] * A[1][1][1]
                     - (A[0][1][0] * A[1][0][0] - A[0][1][1] * A[1][0][1]);
        double detim = A[0][0][0] * A[1][1][1] + A[0][0][1] * A[1][1][0]
                     - (A[0][1][0] * A[1][0][1] + A[0][1][1] * A[1][0][0]);
        double b0re, b0im, b1re, b1im;
        if (n2 == 0) { b0re = A[1][1][0]; b0im = A[1][1][1]; b1re = -A[1][0][0]; b1im = -A[1][0][1]; }
        else         { b0re = -A[0][1][0]; b0im = -A[0][1][1]; b1re = A[0][0][0]; b1im = A[0][0][1]; }
        double dmag = detre * detre + detim * detim;
        double t0re = (b0re * detre + b0im * detim) / dmag, t0im = (b0im * detre - b0re * detim) / dmag;
        double t1re = (b1re * detre + b1im * detim) / dmag, t1im = (b1im * detre - b1re * detim) / dmag;
        double pre = t0re * t1re + t0im * t1im, pim = t0re * t1im - t0im * t1re;
        double quad = d00 * (t0re * t0re + t0im * t0im) + d11 * (t1re * t1re + t1im * t1im)
                    + 2.0 * (dre * pre - dim * pim);
        double denom = sqrt(quad + (double)EPS);
        double w0re = t0re / denom, w0im = -t0im / denom;
        double w1re = t1re / denom, w1im = -t1im / denom;
        Wd[n2][0][0] = w0re; Wd[n2][0][1] = w0im;
        Wd[n2][1][0] = w1re; Wd[n2][1][1] = w1im;
        W2[i * 4 + n2 * 2 + 0] = make_float2((float)w0re, (float)w0im);
        W2[i * 4 + n2 * 2 + 1] = make_float2((float)w1re, (float)w1im);
      }
      if (DO_A) {
        sbc[0] = (float)(Wd[0][0][0] * Wd[0][0][0] + Wd[0][0][1] * Wd[0][0][1]);
        sbc[1] = (float)(Wd[0][1][0] * Wd[0][1][0] + Wd[0][1][1] * Wd[0][1][1]);
        sbc[2] = (float)(2.0 * (Wd[0][0][0] * Wd[0][1][0] + Wd[0][0][1] * Wd[0][1][1]));
        sbc[3] = (float)(-2.0 * (Wd[0][0][1] * Wd[0][1][0] - Wd[0][0][0] * Wd[0][1][1]));
        sbc[4] = (float)(Wd[1][0][0] * Wd[1][0][0] + Wd[1][0][1] * Wd[1][0][1]);
        sbc[5] = (float)(Wd[1][1][0] * Wd[1][1][0] + Wd[1][1][1] * Wd[1][1][1]);
        sbc[6] = (float)(2.0 * (Wd[1][0][0] * Wd[1][1][0] + Wd[1][0][1] * Wd[1][1][1]));
        sbc[7] = (float)(-2.0 * (Wd[1][0][1] * Wd[1][1][0] - Wd[1][0][0] * Wd[1][1][1]));
      }
    }
  } else {
    if (t == 0) {
      float2 w00 = W2[i * 4 + 0], w01 = W2[i * 4 + 1], w10 = W2[i * 4 + 2], w11 = W2[i * 4 + 3];
      sbc[0] = w00.x * w00.x + w00.y * w00.y;
      sbc[1] = w01.x * w01.x + w01.y * w01.y;
      sbc[2] = 2.f * (w00.x * w01.x + w00.y * w01.y);
      sbc[3] = -2.f * (w00.y * w01.x - w00.x * w01.y);
      sbc[4] = w10.x * w10.x + w10.y * w10.y;
      sbc[5] = w11.x * w11.x + w11.y * w11.y;
      sbc[6] = 2.f * (w10.x * w11.x + w10.y * w11.y);
      sbc[7] = -2.f * (w10.y * w11.x - w10.x * w11.y);
    }
  }

  if constexpr (DO_A) {
    __syncthreads();
    const f32x2 alp = (f32x2){sbc[0], sbc[4]}, btp = (f32x2){sbc[1], sbc[5]};
    const f32x2 gmp = (f32x2){sbc[2], sbc[6]}, dlp = (f32x2){sbc[3], sbc[7]};
    f32x2 nT[K_], dT[K_];  // {src0, src1} each
#pragma unroll
    for (int k = 0; k < K_; k++) { nT[k] = sp(0.f); dT[k] = sp(0.f); }
    float2* y0r = YdR2 + (size_t)i * JHP;
    float2* y1r = YdR2 + (size_t)(I_ + i) * JHP;
#pragma unroll 1
    for (int l = 0; l < NL; l++) {
      int j2 = t + l * 256;
      float4 x0 = x0r[j2], x1 = x1r[j2];
      float4 vp[K_];
      f32x2 rA = sp(0.f), rB = sp(0.f);
#pragma unroll
      for (int k = 0; k < K_; k++) {
        vp[k] = V4[(size_t)k * JHP + j2];
        rA += Tp[k] * xy(vp[k]);
        rB += Tp[k] * zw(vp[k]);
      }
      float n00a = x0.x * x0.x + x0.y * x0.y, n00b = x0.z * x0.z + x0.w * x0.w;
      float n11a = x1.x * x1.x + x1.y * x1.y, n11b = x1.z * x1.z + x1.w * x1.w;
      float crea = x0.x * x1.x + x0.y * x1.y, creb = x0.z * x1.z + x0.w * x1.w;
      float cima = x0.y * x1.x - x0.x * x1.y, cimb = x0.w * x1.z - x0.z * x1.w;
      f32x2 aA = alp * n00a + btp * n11a + gmp * crea + dlp * cima;
      f32x2 aB = alp * n00b + btp * n11b + gmp * creb + dlp * cimb;
      f32x2 ydrA = aA * (f32x2){frcp(rA.x * rA.x + EPS), frcp(rA.y * rA.y + EPS)};
      f32x2 ydrB = aB * (f32x2){frcp(rB.x * rB.x + EPS), frcp(rB.y * rB.y + EPS)};
      f32x2 rdA = (f32x2){frcp(rA.x + EPS), frcp(rA.y + EPS)};
      f32x2 rdB = (f32x2){frcp(rB.x + EPS), frcp(rB.y + EPS)};
      y0r[j2] = make_float2(ydrA.x, ydrB.x);
      y1r[j2] = make_float2(ydrA.y, ydrB.y);
#pragma unroll
      for (int k = 0; k < K_; k++) {
        nT[k] += ydrA * xy(vp[k]) + ydrB * zw(vp[k]);
        dT[k] += rdA * xy(vp[k]) + rdB * zw(vp[k]);
      }
    }
#pragma unroll
    for (int k = 0; k < K_; k++) {
      float a = waveRed(nT[k].x); if (lane == 0) sred[wave][k] = a;
      float b = waveRed(dT[k].x); if (lane == 0) sred[wave][8 + k] = b;
      float c = waveRed(nT[k].y); if (lane == 0) sred[wave][16 + k] = c;
      float d = waveRed(dT[k].y); if (lane == 0) sred[wave][24 + k] = d;
    }
    __syncthreads();
    if (t < 32) sout[t] = sred[0][t] + sred[1][t] + sred[2][t] + sred[3][t];
    __syncthreads();
    if (t < 16) {
      int n = t >> 3, k = t & 7;
      float num = sout[n * 16 + k];
      float den = sout[n * 16 + 8 + k];
      float told = T[n * I_ * K_ + i * K_ + k];
      T[n * I_ * K_ + i * K_ + k] = told * sqrtf(num / (den + EPS));
    }
  }
}

// -------- pass B: partial I-reductions for the V update (j-pair packed f32x2) --------
__global__ __launch_bounds__(TJB, 4) void k_passB(const float* __restrict__ T,
                                                  const float4* __restrict__ V4,
                                                  const float2* __restrict__ YdR2,
                                                  float2* __restrict__ partial2, int iseg) {
  int t = threadIdx.x;
  int jt = blockIdx.x, s = blockIdx.y, n = blockIdx.z;
  int j2 = jt * TJB + t;  // pair index, < JHP (pads read zeros, writes guarded)
  f32x2 va2[K_];          // {v(2j), v(2j+1)} of this source
#pragma unroll
  for (int k = 0; k < K_; k++) {
    float4 vp = V4[(size_t)k * JHP + j2];
    va2[k] = (n == 0) ? (f32x2){vp.x, vp.z} : (f32x2){vp.y, vp.w};
  }
  int i0 = s * iseg, i1 = min(i0 + iseg, I_);
  const float2* yb = YdR2 + (size_t)n * I_ * JHP;
  const float* Tb = T + (size_t)n * I_ * K_;
  f32x2 nV[K_], dV[K_];
#pragma unroll
  for (int k = 0; k < K_; k++) { nV[k] = sp(0.f); dV[k] = sp(0.f); }
#pragma unroll 4
  for (int i = i0; i < i1; i++) {
    const float4* tp = (const float4*)(Tb + i * K_);
    float4 t03 = tp[0], t47 = tp[1];
    float Tn[K_] = {t03.x, t03.y, t03.z, t03.w, t47.x, t47.y, t47.z, t47.w};
    float2 yl = yb[(size_t)i * JHP + j2];
    f32x2 y = (f32x2){yl.x, yl.y};
    f32x2 R = sp(0.f);
#pragma unroll
    for (int k = 0; k < K_; k++) R += sp(Tn[k]) * va2[k];
    f32x2 rd = (f32x2){frcp(R.x + EPS), frcp(R.y + EPS)};
#pragma unroll
    for (int k = 0; k < K_; k++) {
      nV[k] += sp(Tn[k]) * y;
      dV[k] += sp(Tn[k]) * rd;
    }
  }
  if (j2 < JH) {
    size_t b0 = (size_t)((s * 2 + n) * 2 + 0) * K_ * JH;
    size_t b1 = (size_t)((s * 2 + n) * 2 + 1) * K_ * JH;
#pragma unroll
    for (int k = 0; k < K_; k++) {
      partial2[b0 + (size_t)k * JH + j2] = make_float2(nV[k].x, nV[k].y);
      partial2[b1 + (size_t)k * JH + j2] = make_float2(dV[k].x, dV[k].y);
    }
  }
}

// ---------------- finalize V: one thread per (n,k,j) ----------------
__global__ void k_finV(const float* __restrict__ partial, float* __restrict__ Vf, int nseg) {
  int idx = blockIdx.x * 256 + threadIdx.x;
  if (idx >= 2 * K_ * J_) return;
  int n = idx / (K_ * J_);
  int rem = idx - n * (K_ * J_);
  int k = rem / J_, j = rem - k * J_;
  float num = 0.f, den = 0.f;
  for (int s = 0; s < nseg; s++) {
    num += partial[((size_t)((s * 2 + n) * 2 + 0) * K_ + k) * J_ + j];
    den += partial[((size_t)((s * 2 + n) * 2 + 1) * K_ + k) * J_ + j];
  }
  float res = sqrtf(num / (den + EPS));
  Vf[((size_t)k * JP + j) * 2 + n] *= res;
}

// ---------------- final output: Y = W X, transposed to (N,J,I) ----------------
__global__ __launch_bounds__(256) void k_output(const float2* __restrict__ Xt,
                                                const float2* __restrict__ W2,
                                                float2* __restrict__ out) {
  __shared__ float2 tile[2][32][33];
  int i0 = blockIdx.x * 32, j0 = blockIdx.y * 32;
  int tx = threadIdx.x & 31, ty = threadIdx.x >> 5;
  for (int r = ty; r < 32; r += 8) {
    int i = i0 + r, j = j0 + tx;
    if (i < I_ && j < J_) {
      float2 w00 = W2[i * 4 + 0], w01 = W2[i * 4 + 1], w10 = W2[i * 4 + 2], w11 = W2[i * 4 + 3];
      float2 x0 = Xt[(size_t)i * JP + j], x1 = Xt[((size_t)I_ + i) * JP + j];
      tile[0][r][tx] = make_float2(w00.x * x0.x - w00.y * x0.y + w01.x * x1.x - w01.y * x1.y,
                                   w00.x * x0.y + w00.y * x0.x + w01.x * x1.y + w01.y * x1.x);
      tile[1][r][tx] = make_float2(w10.x * x0.x - w10.y * x0.y + w11.x * x1.x - w11.y * x1.y,
                                   w10.x * x0.y + w10.y * x0.x + w11.x * x1.y + w11.y * x1.x);
    }
  }
  __syncthreads();
  for (int r = ty; r < 32; r += 8) {
    int j = j0 + r, i = i0 + tx;
    if (i < I_ && j < J_) {
      out[((size_t)0 * J_ + j) * I_ + i] = tile[0][tx][r];
      out[((size_t)1 * J_ + j) * I_ + i] = tile[1][tx][r];
    }
  }
}

extern "C" void kernel_launch(void* const* d_in, const int* in_sizes, int n_in,
                              void* d_out, int out_size, void* d_ws, size_t ws_size,
                              hipStream_t stream) {
  const float* X = (const float*)d_in[0];
  const float* Tin = (const float*)d_in[1];
  const float* Vin = (const float*)d_in[2];

  char* ws = (char*)d_ws;
  size_t off = 0;
  auto alloc = [&](size_t bytes) {
    void* p = ws + off;
    off = (off + bytes + 255) & ~(size_t)255;
    return p;
  };
  float2* Xt = (float2*)alloc((size_t)2 * I_ * JP * sizeof(float2));
  float2* YdR2 = (float2*)alloc((size_t)2 * I_ * JHP * sizeof(float2));
  float2* V2 = (float2*)alloc((size_t)K_ * JP * sizeof(float2));
  float* T = (float*)alloc((size_t)2 * I_ * K_ * sizeof(float));
  float2* W2 = (float2*)alloc((size_t)I_ * 4 * sizeof(float2));
  size_t per_seg = (size_t)2 * 2 * K_ * J_ * sizeof(float);
  int nseg = (off + 64 * per_seg <= ws_size) ? 64 : ((off + 32 * per_seg <= ws_size) ? 32 : 16);
  float* partial = (float*)alloc((size_t)nseg * per_seg);
  int iseg = (I_ + nseg - 1) / nseg;
  (void)in_sizes; (void)n_in; (void)out_size;

  const float4* Xt4 = (const float4*)Xt;
  const float4* V4 = (const float4*)V2;

  k_init<<<(I_ * K_ * 2 + 255) / 256, 256, 0, stream>>>(Tin, Vin, T, V2, W2);
  dim3 tg((I_ + 31) / 32, JP / 32, 2);
  k_transpose<<<tg, 256, 0, stream>>>((const float2*)X, Xt);

  // A(0)
  k_CA<false, true><<<I_, 256, 0, stream>>>(Xt4, W2, T, V4, YdR2);
  for (int it = 0; it < NITER; it++) {
    k_passB<<<dim3(NJTP, nseg, 2), TJB, 0, stream>>>(T, V4, YdR2, (float2*)partial, iseg);
    k_finV<<<(2 * K_ * J_ + 255) / 256, 256, 0, stream>>>(partial, (float*)V2, nseg);
    if (it < NITER - 1) {
      k_CA<true, true><<<I_, 256, 0, stream>>>(Xt4, W2, T, V4, YdR2);
    } else {
      k_CA<true, false><<<I_, 256, 0, stream>>>(Xt4, W2, T, V4, YdR2);
    }
  }
  dim3 og((I_ + 31) / 32, (J_ + 31) / 32);
  k_output<<<og, 256, 0, stream>>>(Xt, W2, (float2*)d_out);
}